// Round 17
// baseline (4461.475 us; speedup 1.0000x reference)
//
#include <hip/hip_runtime.h>
#include <hip/hip_fp16.h>

// LSTM forecaster: B=256, T=512, D_IN=64, H=1024, out = h_final @ Wout + bout.
// Round 17 = Round 16 VERBATIM + __attribute__((amdgpu_waves_per_eu(2,2))).
// WHY: R12/R16 both show VGPR_Count=128 + FETCH 6.9GB -> the allocator's
// occupancy heuristic targets 4 waves/EU (128-VGPR cap) and rematerializes
// the wfr[4][8] W fragments from memory, burning the bandwidth the 32-unit
// tile was meant to save. __launch_bounds__'s 2nd arg is only a MIN waves/EU;
// amdgpu_waves_per_eu(2,2) pins min=max=2 (the occupancy we actually run:
// 8 waves/WG, 1 WG/CU, 24.7% all session) -> 256-VGPR budget -> W resident.
// Volume model (unfalsified): bypass-read volume = 512KB * (1024/units) per
// step; units=32 -> 16MB/step at ~4.8TB/s measured service ~= 3.6us + ~1us
// compute/handshake. Diagnostic: VGPR>=200 & FETCH~1.2GB => confirmed;
// VGPR=128 again => allocator path closed, R13 structure is terminal.

#define T_STEPS 512
#define HID 1024
#define GRID 256
#define NTHR 512

typedef __attribute__((ext_vector_type(8))) _Float16 half8;
typedef __attribute__((ext_vector_type(4))) float f32x4;
typedef __attribute__((ext_vector_type(2))) float f32x2;

__device__ __forceinline__ float sigm(float v) {
    return __builtin_amdgcn_rcpf(1.0f + __expf(-v));
}
__device__ __forceinline__ float tanh_fast(float v) {
    return 2.0f * __builtin_amdgcn_rcpf(1.0f + __expf(-2.0f * v)) - 1.0f;
}

// Pack W [1088][4096] f32 -> Wp fp16 [ng(32)][kb(136)][col(128)][8]
// col c of group ng -> original column (c&3)*1024 + ng*32 + (c>>2) (gate-interleaved).
__global__ void pack_w(const float* __restrict__ W, _Float16* __restrict__ Wp) {
    int idx = blockIdx.x * 256 + threadIdx.x;
    const int total = 32 * 136 * 128;
    if (idx >= total) return;
    int col = idx & 127;
    int kb = (idx >> 7) % 136;
    int ng = (idx >> 7) / 136;
    int oc = ((col & 3) << 10) + (ng << 5) + (col >> 2);
    const float* src = W + (size_t)(kb * 8) * 4096 + oc;
    _Float16* dst = Wp + (size_t)idx * 8;
#pragma unroll
    for (int j = 0; j < 8; j++) dst[j] = (_Float16)src[(size_t)j * 4096];
}

__global__ void __launch_bounds__(NTHR)
__attribute__((amdgpu_waves_per_eu(2, 2))) lstm_persist(
    const float* __restrict__ x,      // [256][512][64] f32
    const _Float16* __restrict__ Wp,  // packed W fp16
    const float* __restrict__ bias,   // [4096] f32
    _Float16* __restrict__ hbuf,      // [2][128][256][8] fp16  (kb, b, kin)
    float* __restrict__ hfinal,       // [256][1024] f32
    unsigned int* bar)                // [256] arrival words, 64B apart
{
    __shared__ float P[4 * 128 * 32];  // 64 KiB: 4 planes [c(128)][row(32)], XOR-swizzled
    _Float16* hstage = (_Float16*)P;   // 2 KiB overlay on plane 0 ([32 rows][32 units])

    int wg = blockIdx.x;
    int mg = wg >> 5;      // 0..7  : batch rows [32mg, 32mg+32)
    int ng = wg & 31;      // 0..31 : units [32ng, 32ng+32) -> 128 gate cols
    int B0 = mg << 5;

    int tid = threadIdx.x;
    int wave = tid >> 6;   // 0..7
    int lane = tid & 63;
    int l15 = lane & 15, l4 = lane >> 4;
    int bb = tid & 31;     // activation: batch row
    int us = tid >> 5;     // activation: unit pair 0..15 -> units 2us, 2us+1

    // per-thread bias: q -> (b=bb, u=2us+q), gates i,f,g,o
    float breg[2][4];
#pragma unroll
    for (int q = 0; q < 2; q++) {
        int u = (us << 1) + q;
#pragma unroll
        for (int g = 0; g < 4; g++) breg[q][g] = bias[(g << 10) + (ng << 5) + u];
    }

    float cst[2] = {0.f, 0.f};

    const size_t HB = (size_t)128 * 256 * 8;
    const _Float16* WpBase = Wp + (size_t)ng * 136 * 1024;

    // ---- W prologue: wave w owns h-chunks {2+w, 10+w, 18+w, 26+w} (covers 2..33),
    //      fragments register-resident for all 512 steps: 32 half8 = 128 VGPR ----
    half8 wfr[4][8];
#pragma unroll
    for (int j = 0; j < 4; j++) {
        int kb = ((2 + wave + 8 * j) << 2) + l4;  // 8..135
        const _Float16* wp = WpBase + ((size_t)kb << 10);
#pragma unroll
        for (int nn = 0; nn < 8; nn++) wfr[j][nn] = *(const half8*)(wp + (((nn << 4) + l15) << 3));
    }

    f32x4 acc[2][8];
#pragma unroll
    for (int i = 0; i < 2; i++)
#pragma unroll
        for (int j = 0; j < 8; j++) acc[i][j] = (f32x4){0.f, 0.f, 0.f, 0.f};

    // x(tt) @ Wx into acc — waves 2,3 only (x chunk = wave-2); bx loaded per call
    // in two halves of 4 to cap transient registers.
    auto XPREP = [&](int tt) {
        if (wave == 2 || wave == 3) {
            int kb = ((wave - 2) << 2) + l4;  // 0..7
            half8 v[2];
#pragma unroll
            for (int mm = 0; mm < 2; mm++) {
                const float* xp = x + ((size_t)(B0 + (mm << 4) + l15) * T_STEPS + tt) * 64 + (kb << 3);
                f32x4 lo = *(const f32x4*)xp;
                f32x4 hi = *(const f32x4*)(xp + 4);
                half8 t;
                t[0] = (_Float16)lo[0]; t[1] = (_Float16)lo[1];
                t[2] = (_Float16)lo[2]; t[3] = (_Float16)lo[3];
                t[4] = (_Float16)hi[0]; t[5] = (_Float16)hi[1];
                t[6] = (_Float16)hi[2]; t[7] = (_Float16)hi[3];
                v[mm] = t;
            }
            const _Float16* wp = WpBase + ((size_t)kb << 10);
#pragma unroll
            for (int h2 = 0; h2 < 2; h2++) {
                half8 bx[4];
#pragma unroll
                for (int i = 0; i < 4; i++) {
                    int nn = (h2 << 2) + i;
                    bx[i] = *(const half8*)(wp + (((nn << 4) + l15) << 3));
                }
#pragma unroll
                for (int mm = 0; mm < 2; mm++)
#pragma unroll
                    for (int i = 0; i < 4; i++)
                        acc[mm][(h2 << 2) + i] =
                            __builtin_amdgcn_mfma_f32_16x16x32_f16(v[mm], bx[i],
                                                                   acc[mm][(h2 << 2) + i], 0, 0, 0);
            }
        }
    };

    XPREP(0);

    for (int t = 0; t < T_STEPS; t++) {
        const _Float16* cur = hbuf + (size_t)(t & 1) * HB;
        _Float16* nxt = hbuf + (size_t)((t + 1) & 1) * HB;

        // ---- h @ Wh: coherent (MALL) u64 atomic loads x2 per frag (proven) ----
#pragma unroll
        for (int j = 0; j < 4; j++) {
            int kb = ((2 + wave + 8 * j) << 2) + l4;  // 8..135
            unsigned long long* hp =
                (unsigned long long*)(cur + (((size_t)(kb - 8) << 8) + B0 + l15) * 8);
            half8 ah[2];
#pragma unroll
            for (int mm = 0; mm < 2; mm++) {
                union { unsigned long long u[2]; half8 h; } cv;
                cv.u[0] = __hip_atomic_load(hp + (mm << 5), __ATOMIC_RELAXED, __HIP_MEMORY_SCOPE_AGENT);
                cv.u[1] = __hip_atomic_load(hp + (mm << 5) + 1, __ATOMIC_RELAXED, __HIP_MEMORY_SCOPE_AGENT);
                ah[mm] = cv.h;
            }
#pragma unroll
            for (int mm = 0; mm < 2; mm++)
#pragma unroll
                for (int nn = 0; nn < 8; nn++)
                    acc[mm][nn] = __builtin_amdgcn_mfma_f32_16x16x32_f16(ah[mm], wfr[j][nn],
                                                                         acc[mm][nn], 0, 0, 0);
        }

        // ---- two-pass cross-wave reduction, 4 planes of 16KB, XOR-swizzled ----
        if (wave < 4) {
            float* Pq = P + (wave << 12);
#pragma unroll
            for (int mm = 0; mm < 2; mm++)
#pragma unroll
                for (int nn = 0; nn < 8; nn++) {
                    int c = (nn << 4) + l15;           // gate col 0..127
                    int bblk = (mm << 2) + l4;         // row block 0..7
                    int word = (c << 5) + (((bblk ^ l15) & 7) << 2);
                    *(f32x4*)&Pq[word] = acc[mm][nn];
                }
        }
        __syncthreads();
        if (wave >= 4) {
            float* Pq = P + ((wave - 4) << 12);
#pragma unroll
            for (int mm = 0; mm < 2; mm++)
#pragma unroll
                for (int nn = 0; nn < 8; nn++) {
                    int c = (nn << 4) + l15;
                    int bblk = (mm << 2) + l4;
                    int word = (c << 5) + (((bblk ^ l15) & 7) << 2);
                    f32x4 v = *(f32x4*)&Pq[word];
                    v += acc[mm][nn];
                    *(f32x4*)&Pq[word] = v;
                }
        }
        __syncthreads();

        // ---- activations: thread handles (b=bb, u=2us+q), q=0,1 ----
        union { _Float16 h2[2]; unsigned int u; } hs;
        float hvf[2];
#pragma unroll
        for (int q = 0; q < 2; q++) {
            int u = (us << 1) + q;
            float g4[4];
#pragma unroll
            for (int g = 0; g < 4; g++) {
                int c = (u << 2) + g;
                int word = (c << 5) + (((((bb >> 2) ^ c) & 7) << 2) | (bb & 3));
                float s = breg[q][g];
#pragma unroll
                for (int w = 0; w < 4; w++) s += P[(w << 12) + word];
                g4[g] = s;
            }
            float ig = sigm(g4[0]);
            float fg = sigm(g4[1]);
            float gg = tanh_fast(g4[2]);
            float og = sigm(g4[3]);
            float cv = fg * cst[q] + ig * gg;
            cst[q] = cv;
            float hv = og * tanh_fast(cv);
            hs.h2[q] = (_Float16)hv;
            hvf[q] = hv;
        }
        if (t == T_STEPS - 1) {
            int ug0 = (ng << 5) + (us << 1);
            f32x2 hv2; hv2[0] = hvf[0]; hv2[1] = hvf[1];
            *(f32x2*)&hfinal[(size_t)(B0 + bb) * HID + ug0] = hv2;
            break;  // uniform; no h publish after last step
        }

        // ---- packed h publish: 4B -> overlay tile -> 128 threads x 2 u64 atomic stores ----
        __syncthreads();  // S_act: ALL P reads complete before overlay writes
        *(unsigned int*)&hstage[(bb << 5) + (us << 1)] = hs.u;
        __syncthreads();  // S_pack: overlay tile complete
        if (tid < 128) {
            int row = tid >> 2, q = tid & 3;  // batch row 0..31, 8-unit quarter 0..3
            union { half8 h; unsigned long long u[2]; } v;
            v.h = *(const half8*)&hstage[(row << 5) + (q << 3)];
            // dst: hbuf[nxt][kb'=4ng+q][B0+row][0..7] (16B, aligned)
            unsigned long long* dst =
                (unsigned long long*)(nxt + (((size_t)((ng << 2) + q) << 8) + B0 + row) * 8);
            __hip_atomic_store(dst, v.u[0], __ATOMIC_RELAXED, __HIP_MEMORY_SCOPE_AGENT);
            __hip_atomic_store(dst + 1, v.u[1], __ATOMIC_RELAXED, __HIP_MEMORY_SCOPE_AGENT);
        }
        asm volatile("s_waitcnt vmcnt(0)" ::: "memory");  // h(t) ack'd at MALL (proven)
        __syncthreads();  // S3a: all packed stores complete

        if (tid == 0)
            __hip_atomic_store(bar + (wg << 4), (unsigned int)(t + 1), __ATOMIC_RELAXED,
                               __HIP_MEMORY_SCOPE_AGENT);
        // reset acc and fold in x(t+1) while the mg-group's producers arrive
#pragma unroll
        for (int i = 0; i < 2; i++)
#pragma unroll
            for (int j = 0; j < 8; j++) acc[i][j] = (f32x4){0.f, 0.f, 0.f, 0.f};
        XPREP(t + 1);
        // mg-group-local barrier: 32 lanes of wave 4 poll the group's 32 arrival words
        if (tid >= 256 && tid < 288) {
            const unsigned int* ap = bar + (((mg << 5) + (tid - 256)) << 4);
            while (__hip_atomic_load(ap, __ATOMIC_RELAXED, __HIP_MEMORY_SCOPE_AGENT) <
                   (unsigned int)(t + 1)) {
                __builtin_amdgcn_s_sleep(1);
            }
        }
        __syncthreads();
    }
}

// out[b][j] = bout[j] + sum_k hfinal[b][k] * Wout[k][j]   (256 blocks x 64 threads)
__global__ void proj_kernel(const float* __restrict__ hfinal, const float* __restrict__ Wout,
                            const float* __restrict__ bout, float* __restrict__ out) {
    int b = blockIdx.x;
    int l = threadIdx.x;
    float acc[24];
#pragma unroll
    for (int j = 0; j < 24; j++) acc[j] = 0.f;
    for (int i = 0; i < 16; i++) {
        int k = i * 64 + l;
        float h = hfinal[(size_t)b * HID + k];
        const float* wr = Wout + (size_t)k * 24;
#pragma unroll
        for (int j = 0; j < 24; j++) acc[j] += h * wr[j];
    }
    __shared__ float red[24][65];
#pragma unroll
    for (int j = 0; j < 24; j++) red[j][l] = acc[j];
    __syncthreads();
    if (l < 24) {
        float s = bout[l];
#pragma unroll
        for (int i = 0; i < 64; i++) s += red[l][i];
        out[b * 24 + l] = s;
    }
}

extern "C" void kernel_launch(void* const* d_in, const int* in_sizes, int n_in,
                              void* d_out, int out_size, void* d_ws, size_t ws_size,
                              hipStream_t stream) {
    const float* x = (const float*)d_in[0];     // [256][512][64]
    const float* W = (const float*)d_in[1];     // [1088][4096]
    const float* b = (const float*)d_in[2];     // [4096]
    const float* Wout = (const float*)d_in[3];  // [1024][24]
    const float* bout = (const float*)d_in[4];  // [24]
    float* out = (float*)d_out;

    char* ws = (char*)d_ws;
    _Float16* Wp = (_Float16*)ws;                                 // 8,912,896 B
    _Float16* hbuf = (_Float16*)(ws + 8912896);                   // 1,048,576 B
    float* hfinal = (float*)(ws + 8912896 + 1048576);             // 1,048,576 B
    unsigned int* bar = (unsigned int*)(ws + 8912896 + 2097152);  // 16,384 B

    // zero h buffer 0 (h_init = 0) and barrier words, every call (graph-replay safe)
    hipMemsetAsync(hbuf, 0, (size_t)128 * 256 * 8 * sizeof(_Float16), stream);
    hipMemsetAsync(bar, 0, 16384, stream);

    pack_w<<<(32 * 136 * 128 + 255) / 256, 256, 0, stream>>>(W, Wp);

    void* args[6];
    args[0] = (void*)&x;
    args[1] = (void*)&Wp;
    args[2] = (void*)&b;
    args[3] = (void*)&hbuf;
    args[4] = (void*)&hfinal;
    args[5] = (void*)&bar;
    hipLaunchCooperativeKernel((void*)lstm_persist, dim3(GRID), dim3(NTHR), args, 0, stream);

    proj_kernel<<<256, 64, 0, stream>>>(hfinal, Wout, bout, out);
}

// Round 18
// 3490.718 us; speedup vs baseline: 1.2781x; 1.2781x over previous
//
#include <hip/hip_runtime.h>
#include <hip/hip_fp16.h>

// LSTM forecaster: B=256, T=512, D_IN=64, H=1024, out = h_final @ Wout + bout.
// Round 18 = REVERT to Round 13 verbatim (session best: 3.49ms, passed).
// Rationale: R12/R16/R17 all failed the pre-committed diagnostic (VGPR_Count
// pinned at 128 -> wfr[4][8] W streams from memory, FETCH 6.9GB) -> the
// 32-unit tile's 2x volume reduction is compiler-blocked. R13's structure is
// at its floor: 32 MB/step of L2-bypass h reads / ~4.8 TB/s coherent-path
// service ~= 6.6us of the measured 6.8us step (~95%). All volume/latency
// alternatives were falsified on HW: cached sharing (R4, R14), two-chain
// pipeline (R15), packed stores (R10, kept), smaller tile (R12/R16/R17).
// Structure: grid=256 (1 WG/CU), 8 waves/WG, WG tile = 64 batch x 16 units;
// W register-resident (wfr[4][4]); h exchange via agent-scope u64 atomics
// (only HW-verified coherent primitive this session); wave-0 packed publish
// + vmcnt drain + per-WG monotonic flag; m-group poll wave; XPREP(t+1)
// overlaps the barrier window.

#define T_STEPS 512
#define HID 1024
#define GRID 256
#define NTHR 512

typedef __attribute__((ext_vector_type(8))) _Float16 half8;
typedef __attribute__((ext_vector_type(4))) float f32x4;
typedef __attribute__((ext_vector_type(2))) float f32x2;

__device__ __forceinline__ float sigm(float v) {
    return __builtin_amdgcn_rcpf(1.0f + __expf(-v));
}
__device__ __forceinline__ float tanh_fast(float v) {
    return 2.0f * __builtin_amdgcn_rcpf(1.0f + __expf(-2.0f * v)) - 1.0f;
}

// Pack W [1088][4096] f32 -> Wp fp16 [n(64)][kb(136)][col(64)][kin(8)]
// col c of group n maps to original column (c&3)*1024 + n*16 + (c>>2)  (gate-interleaved).
__global__ void pack_w(const float* __restrict__ W, _Float16* __restrict__ Wp) {
    int idx = blockIdx.x * 256 + threadIdx.x;
    const int total = 64 * 136 * 64;
    if (idx >= total) return;
    int col = idx & 63;
    int kb = (idx >> 6) % 136;
    int n = (idx >> 6) / 136;
    int oc = ((col & 3) << 10) + (n << 4) + (col >> 2);
    const float* src = W + (size_t)(kb * 8) * 4096 + oc;
    _Float16* dst = Wp + (size_t)idx * 8;
#pragma unroll
    for (int j = 0; j < 8; j++) dst[j] = (_Float16)src[(size_t)j * 4096];
}

__global__ void __launch_bounds__(NTHR, 2) lstm_persist(
    const float* __restrict__ x,      // [256][512][64] f32
    const _Float16* __restrict__ Wp,  // packed W fp16
    const float* __restrict__ bias,   // [4096] f32
    _Float16* __restrict__ hbuf,      // [2][128][256][8] fp16  (kb, b, kin)
    float* __restrict__ hfinal,       // [256][1024] f32
    unsigned int* bar)                // [256] arrival words, 64B apart
{
    __shared__ float P[4 * 64 * 64];  // 64 KiB (proven size)
    _Float16* hstage = (_Float16*)P;  // 2 KiB overlay on plane 0 ([64][16])

    int wg = blockIdx.x;
    // XCD-aware mapping: XCD x gets n in [8x,8x+8) for all 4 m.
    int xcd = wg & 7, slot = wg >> 3;
    int n = (xcd << 3) + (slot & 7);  // 0..63
    int m = slot >> 3;                 // 0..3  (m-group = wgs [64m, 64m+64))
    int B0 = m << 6;

    int tid = threadIdx.x;
    int wave = tid >> 6;   // 0..7
    int lane = tid & 63;
    int l15 = lane & 15, l4 = lane >> 4;
    int bb = tid & 63;
    int u0 = tid >> 6;     // activation: units 2*u0, 2*u0+1

    // per-thread bias: q -> (b=bb, u=2*u0+q), gates i,f,g,o
    float breg[2][4];
#pragma unroll
    for (int q = 0; q < 2; q++) {
        int u = (u0 << 1) + q;
#pragma unroll
        for (int g = 0; g < 4; g++) breg[q][g] = bias[(g << 10) + (n << 4) + u];
    }

    float cst[2] = {0.f, 0.f};

    const size_t HB = (size_t)128 * 256 * 8;
    const _Float16* WpBase = Wp + (size_t)n * 136 * 64 * 8;

    // ---- W prologue: wave w owns h-chunks {2+w, 10+w, 18+w, 26+w} (covers 2..33),
    //      fragments register-resident for all 512 steps ----
    half8 wfr[4][4];
#pragma unroll
    for (int j = 0; j < 4; j++) {
        int kb = ((2 + wave + 8 * j) << 2) + l4;  // 8..135
        const _Float16* wp = WpBase + ((size_t)kb << 9);
#pragma unroll
        for (int nn = 0; nn < 4; nn++) wfr[j][nn] = *(const half8*)(wp + (((nn << 4) + l15) << 3));
    }

    // ---- Wx prologue: waves 2,3 keep their x-chunk W fragments resident ----
    half8 bxr[4];
    if (wave == 2 || wave == 3) {
        int kb = ((wave - 2) << 2) + l4;  // 0..7
        const _Float16* wp = WpBase + ((size_t)kb << 9);
#pragma unroll
        for (int nn = 0; nn < 4; nn++) bxr[nn] = *(const half8*)(wp + (((nn << 4) + l15) << 3));
    }

    f32x4 acc[4][4];
#pragma unroll
    for (int i = 0; i < 4; i++)
#pragma unroll
        for (int j = 0; j < 4; j++) acc[i][j] = (f32x4){0.f, 0.f, 0.f, 0.f};

    // x(tt) @ Wx into acc — waves 2,3 only; W from registers, x cached loads
    auto XPREP = [&](int tt) {
        if (wave == 2 || wave == 3) {
            int kb = ((wave - 2) << 2) + l4;  // 0..7
#pragma unroll
            for (int mm = 0; mm < 4; mm++) {
                const float* xp = x + ((size_t)(B0 + (mm << 4) + l15) * T_STEPS + tt) * 64 + (kb << 3);
                f32x4 lo = *(const f32x4*)xp;
                f32x4 hi = *(const f32x4*)(xp + 4);
                half8 v;
                v[0] = (_Float16)lo[0]; v[1] = (_Float16)lo[1];
                v[2] = (_Float16)lo[2]; v[3] = (_Float16)lo[3];
                v[4] = (_Float16)hi[0]; v[5] = (_Float16)hi[1];
                v[6] = (_Float16)hi[2]; v[7] = (_Float16)hi[3];
#pragma unroll
                for (int nn = 0; nn < 4; nn++)
                    acc[mm][nn] = __builtin_amdgcn_mfma_f32_16x16x32_f16(v, bxr[nn], acc[mm][nn], 0, 0, 0);
            }
        }
    };

    XPREP(0);

    for (int t = 0; t < T_STEPS; t++) {
        const _Float16* cur = hbuf + (size_t)(t & 1) * HB;
        _Float16* nxt = hbuf + (size_t)((t + 1) & 1) * HB;

        // ---- h @ Wh: coherent (MALL) u64 atomic loads x2 per frag (proven) ----
#pragma unroll
        for (int j = 0; j < 4; j++) {
            int kb = ((2 + wave + 8 * j) << 2) + l4;  // 8..135
            unsigned long long* hp =
                (unsigned long long*)(cur + (((size_t)(kb - 8) << 8) + B0 + l15) * 8);
            half8 ah[4];
#pragma unroll
            for (int mm = 0; mm < 4; mm++) {
                union { unsigned long long u[2]; half8 h; } cv;
                cv.u[0] = __hip_atomic_load(hp + (mm << 5), __ATOMIC_RELAXED, __HIP_MEMORY_SCOPE_AGENT);
                cv.u[1] = __hip_atomic_load(hp + (mm << 5) + 1, __ATOMIC_RELAXED, __HIP_MEMORY_SCOPE_AGENT);
                ah[mm] = cv.h;
            }
#pragma unroll
            for (int mm = 0; mm < 4; mm++)
#pragma unroll
                for (int nn = 0; nn < 4; nn++)
                    acc[mm][nn] = __builtin_amdgcn_mfma_f32_16x16x32_f16(ah[mm], wfr[j][nn],
                                                                         acc[mm][nn], 0, 0, 0);
        }

        // ---- two-pass cross-wave reduction, 4 planes of 16KB, XOR-swizzled ----
        if (wave < 4) {
#pragma unroll
            for (int mm = 0; mm < 4; mm++)
#pragma unroll
                for (int nn = 0; nn < 4; nn++) {
                    int c = (nn << 4) + l15;
                    int bblk = (mm << 2) + l4;
                    int word = (((wave << 6) + c) << 6) + (((bblk ^ l15) & 15) << 2);
                    *(f32x4*)&P[word] = acc[mm][nn];
                }
        }
        __syncthreads();
        if (wave >= 4) {
            int pw = wave - 4;
#pragma unroll
            for (int mm = 0; mm < 4; mm++)
#pragma unroll
                for (int nn = 0; nn < 4; nn++) {
                    int c = (nn << 4) + l15;
                    int bblk = (mm << 2) + l4;
                    int word = (((pw << 6) + c) << 6) + (((bblk ^ l15) & 15) << 2);
                    f32x4 v = *(f32x4*)&P[word];
                    v += acc[mm][nn];
                    *(f32x4*)&P[word] = v;
                }
        }
        __syncthreads();

        // ---- activations: thread handles (b=bb, u=2*u0+q), q=0,1 ----
        union { _Float16 h2[2]; unsigned int u; } hs;
        float hvf[2];
#pragma unroll
        for (int q = 0; q < 2; q++) {
            int u = (u0 << 1) + q;
            float g4[4];
#pragma unroll
            for (int g = 0; g < 4; g++) {
                int c = (u << 2) + g;
                int word = (c << 6) + (((((bb >> 2) ^ c) & 15) << 2) | (bb & 3));
                float s = breg[q][g];
#pragma unroll
                for (int w = 0; w < 4; w++) s += P[(w << 12) + word];
                g4[g] = s;
            }
            float ig = sigm(g4[0]);
            float fg = sigm(g4[1]);
            float gg = tanh_fast(g4[2]);
            float og = sigm(g4[3]);
            float cv = fg * cst[q] + ig * gg;
            cst[q] = cv;
            float hv = og * tanh_fast(cv);
            hs.h2[q] = (_Float16)hv;
            hvf[q] = hv;
        }
        if (t == T_STEPS - 1) {
            int ug0 = (n << 4) + (u0 << 1);
            f32x2 hv2; hv2[0] = hvf[0]; hv2[1] = hvf[1];
            *(f32x2*)&hfinal[(size_t)(B0 + bb) * HID + ug0] = hv2;
            break;  // uniform; no h publish after last step
        }

        // ---- pack h into overlay tile ----
        __syncthreads();  // S_act: ALL P reads complete before overlay writes
        *(unsigned int*)&hstage[(bb << 4) + (u0 << 1)] = hs.u;
        __syncthreads();  // S_pack: overlay tile complete

        // ---- wave 0 ALONE: publish 128x16B, drain, flag (off other waves' path) ----
        if (wave == 0) {
#pragma unroll
            for (int it = 0; it < 2; it++) {
                int item = lane + (it << 6);         // 0..127
                int row = item >> 1, hf = item & 1;  // batch row, 8-unit half
                union { half8 h; unsigned long long u[2]; } v;
                v.h = *(const half8*)&hstage[(row << 4) + (hf << 3)];
                // dst: hbuf[nxt][kb'=2n+hf][B0+row][0..7] (16B, 8B-aligned)
                unsigned long long* dst =
                    (unsigned long long*)(nxt + (((size_t)((n << 1) + hf) << 8) + B0 + row) * 8);
                __hip_atomic_store(dst, v.u[0], __ATOMIC_RELAXED, __HIP_MEMORY_SCOPE_AGENT);
                __hip_atomic_store(dst + 1, v.u[1], __ATOMIC_RELAXED, __HIP_MEMORY_SCOPE_AGENT);
            }
            asm volatile("s_waitcnt vmcnt(0)" ::: "memory");  // wave-0 stores ack'd at MALL
            if (lane == 0)
                __hip_atomic_store(bar + (wg << 4), (unsigned int)(t + 1), __ATOMIC_RELAXED,
                                   __HIP_MEMORY_SCOPE_AGENT);
        }

        // ---- all waves: reset acc; waves 2,3 fold x(t+1); poll wave waits ----
#pragma unroll
        for (int i = 0; i < 4; i++)
#pragma unroll
            for (int j = 0; j < 4; j++) acc[i][j] = (f32x4){0.f, 0.f, 0.f, 0.f};
        XPREP(t + 1);
        // m-group-local barrier: one wave polls the group's 64 arrival words
        if (tid >= 256 && tid < 320) {
            const unsigned int* ap = bar + (((m << 6) + (tid - 256)) << 4);
            while (__hip_atomic_load(ap, __ATOMIC_RELAXED, __HIP_MEMORY_SCOPE_AGENT) <
                   (unsigned int)(t + 1)) {
                __builtin_amdgcn_s_sleep(1);
            }
        }
        __syncthreads();
    }
}

// out[b][j] = bout[j] + sum_k hfinal[b][k] * Wout[k][j]   (256 blocks x 64 threads)
__global__ void proj_kernel(const float* __restrict__ hfinal, const float* __restrict__ Wout,
                            const float* __restrict__ bout, float* __restrict__ out) {
    int b = blockIdx.x;
    int l = threadIdx.x;
    float acc[24];
#pragma unroll
    for (int j = 0; j < 24; j++) acc[j] = 0.f;
    for (int i = 0; i < 16; i++) {
        int k = i * 64 + l;
        float h = hfinal[(size_t)b * HID + k];
        const float* wr = Wout + (size_t)k * 24;
#pragma unroll
        for (int j = 0; j < 24; j++) acc[j] += h * wr[j];
    }
    __shared__ float red[24][65];
#pragma unroll
    for (int j = 0; j < 24; j++) red[j][l] = acc[j];
    __syncthreads();
    if (l < 24) {
        float s = bout[l];
#pragma unroll
        for (int i = 0; i < 64; i++) s += red[l][i];
        out[b * 24 + l] = s;
    }
}

extern "C" void kernel_launch(void* const* d_in, const int* in_sizes, int n_in,
                              void* d_out, int out_size, void* d_ws, size_t ws_size,
                              hipStream_t stream) {
    const float* x = (const float*)d_in[0];     // [256][512][64]
    const float* W = (const float*)d_in[1];     // [1088][4096]
    const float* b = (const float*)d_in[2];     // [4096]
    const float* Wout = (const float*)d_in[3];  // [1024][24]
    const float* bout = (const float*)d_in[4];  // [24]
    float* out = (float*)d_out;

    char* ws = (char*)d_ws;
    _Float16* Wp = (_Float16*)ws;                                 // 8,912,896 B
    _Float16* hbuf = (_Float16*)(ws + 8912896);                   // 1,048,576 B
    float* hfinal = (float*)(ws + 8912896 + 1048576);             // 1,048,576 B
    unsigned int* bar = (unsigned int*)(ws + 8912896 + 2097152);  // 16,384 B

    // zero h buffer 0 (h_init = 0) and barrier words, every call (graph-replay safe)
    hipMemsetAsync(hbuf, 0, (size_t)128 * 256 * 8 * sizeof(_Float16), stream);
    hipMemsetAsync(bar, 0, 16384, stream);

    pack_w<<<(64 * 136 * 64 + 255) / 256, 256, 0, stream>>>(W, Wp);

    void* args[6];
    args[0] = (void*)&x;
    args[1] = (void*)&Wp;
    args[2] = (void*)&b;
    args[3] = (void*)&hbuf;
    args[4] = (void*)&hfinal;
    args[5] = (void*)&bar;
    hipLaunchCooperativeKernel((void*)lstm_persist, dim3(GRID), dim3(NTHR), args, 0, stream);

    proj_kernel<<<256, 64, 0, stream>>>(hfinal, Wout, bout, out);
}